// Round 1
// baseline (275.504 us; speedup 1.0000x reference)
//
#include <hip/hip_runtime.h>
#include <hip/hip_fp16.h>

// CommNet critic forward, fully fused: 1 workgroup = 1 batch (32 agents).
// All GEMMs via v_mfma_f32_16x16x32_f16 (fp32 accumulate). B=2048,A=32,D=128,H=256.
// V2: fused 3-gate GRU passes (shared r/z accumulators), 2 LDS buffers,
//     vectorized staging/comm, shuffle-reduced column sums.

#define NB   2048
#define NA   32
#define DIN  128
#define HID  256
#define SA   264   // f16 row stride for activation LDS tiles (+8 pad -> even bank spread)

typedef _Float16 half8  __attribute__((ext_vector_type(8)));
typedef float    float4v __attribute__((ext_vector_type(4)));

// f16 weight-fragment arena layout in d_ws (element offsets)
#define ENC_OFF    0
#define FOBS_OFF   32768
#define WIH_OFF    98304
#define WHH_OFF    294912
#define PREP_TOTAL 491520   // f16 elements -> 983040 bytes needed in ws

// Pre-arrange weights into exact MFMA B-fragment order, f16:
// frag[((ks*NT + nt)*64 + lane)*8 + j] = W[nt*16 + lane%16][ks*32 + (lane/16)*8 + j]
__global__ void prep_weights(const float* __restrict__ encW, const float* __restrict__ fobsW,
                             const float* __restrict__ wih,  const float* __restrict__ whh,
                             _Float16* __restrict__ prep) {
    int F = blockIdx.x * 256 + threadIdx.x;
    if (F >= PREP_TOTAL) return;
    const float* src; int K, NT, local = F;
    if (F < FOBS_OFF)     { src = encW;  K = 128; NT = 16; }
    else if (F < WIH_OFF) { src = fobsW; K = 256; NT = 16; local = F - FOBS_OFF; }
    else if (F < WHH_OFF) { src = wih;   K = 256; NT = 48; local = F - WIH_OFF; }
    else                  { src = whh;   K = 256; NT = 48; local = F - WHH_OFF; }
    int j    = local & 7;
    int lane = (local >> 3) & 63;
    int t    = local >> 9;
    int nt   = t % NT;
    int ks   = t / NT;
    int col  = nt * 16 + (lane & 15);
    int k    = ks * 32 + ((lane >> 4) << 3) + j;
    prep[F] = (_Float16)src[col * K + k];
}

__device__ __forceinline__ float sigmoid_f(float x) {
    x = fminf(fmaxf(x, -30.f), 30.f);
    return 1.f / (1.f + __expf(-x));
}
__device__ __forceinline__ float tanh_f(float x) {
    x = fminf(fmaxf(x, -15.f), 15.f);
    float e = __expf(-2.f * x);
    return (1.f - e) / (1.f + e);
}

__device__ __forceinline__ void zero22(float4v a[2][2]) {
    float4v z = {0.f, 0.f, 0.f, 0.f};
    a[0][0] = z; a[0][1] = z; a[1][0] = z; a[1][1] = z;
}

// Load one MFMA B-fragment (16 cols x 32 k) either from prepped arena or raw fp32.
__device__ __forceinline__ half8 ldB(const _Float16* __restrict__ prepm, int NT, int nt, int ks,
                                     const float* __restrict__ raw, int K, int use_prep, int lane) {
    if (use_prep)
        return *(const half8*)(prepm + (((ks * NT + nt) * 64 + lane) << 3));
    half8 b;
    int l16 = lane & 15, kq = (lane >> 4) << 3;
    #pragma unroll
    for (int j = 0; j < 8; j++)
        b[j] = (_Float16)raw[(nt * 16 + l16) * K + ks * 32 + kq + j];
    return b;
}

// One wave computes D-tiles (mt in {0,1}) x (ntg0, ntg0+1): out[32 x 32cols] of a GEMM.
template<int KSTEPS>
__device__ __forceinline__ void gemm_tile(const _Float16* __restrict__ Abuf,
        const _Float16* __restrict__ prepm, int NT, int ntg0,
        const float* __restrict__ raw, int K, int use_prep,
        int lane, float4v acc[2][2])
{
    const int l16 = lane & 15;
    const int kq  = (lane >> 4) << 3;
    #pragma unroll
    for (int ks = 0; ks < KSTEPS; ks++) {
        int kbase = ks * 32 + kq;
        half8 a0 = *(const half8*)(Abuf + l16 * SA + kbase);
        half8 a1 = *(const half8*)(Abuf + (16 + l16) * SA + kbase);
        half8 b0 = ldB(prepm, NT, ntg0,     ks, raw, K, use_prep, lane);
        half8 b1 = ldB(prepm, NT, ntg0 + 1, ks, raw, K, use_prep, lane);
        acc[0][0] = __builtin_amdgcn_mfma_f32_16x16x32_f16(a0, b0, acc[0][0], 0, 0, 0);
        acc[0][1] = __builtin_amdgcn_mfma_f32_16x16x32_f16(a0, b1, acc[0][1], 0, 0, 0);
        acc[1][0] = __builtin_amdgcn_mfma_f32_16x16x32_f16(a1, b0, acc[1][0], 0, 0, 0);
        acc[1][1] = __builtin_amdgcn_mfma_f32_16x16x32_f16(a1, b1, acc[1][1], 0, 0, 0);
    }
}

__global__ __launch_bounds__(512) void commnet_fused(
    const float* __restrict__ obs, const _Float16* __restrict__ prep,
    const float* __restrict__ enc_b, const float* __restrict__ fobs_b,
    const float* __restrict__ b_ih, const float* __restrict__ b_hh,
    const float* __restrict__ dec_W, const float* __restrict__ dec_b,
    float* __restrict__ out,
    const float* __restrict__ encW, const float* __restrict__ fobsW,
    const float* __restrict__ wih, const float* __restrict__ whh,
    int use_prep)
{
    const int b    = blockIdx.x;
    const int tid  = threadIdx.x;
    const int lane = tid & 63;
    const int w    = tid >> 6;     // wave 0..7
    const int l16  = lane & 15;
    const int quad = lane >> 4;
    const int kq   = quad << 3;
    const int ntl0 = w * 2;        // this wave's local ntile pair within 256 cols

    __shared__ __align__(16) _Float16 sA[2][NA * SA];
    __shared__ __align__(16) float S[HID];

    // ---- stage obs (fp32 global -> f16 LDS), vectorized: 1 chunk of 8 per thread
    {
        const float* obsb = obs + (size_t)b * NA * DIN;
        int r   = tid >> 4;            // 16 chunks per 128-wide row
        int off = (tid & 15) << 3;
        const float* src = obsb + r * DIN + off;
        float4v v0 = *(const float4v*)(src);
        float4v v1 = *(const float4v*)(src + 4);
        half8 hv;
        hv[0] = (_Float16)v0[0]; hv[1] = (_Float16)v0[1];
        hv[2] = (_Float16)v0[2]; hv[3] = (_Float16)v0[3];
        hv[4] = (_Float16)v1[0]; hv[5] = (_Float16)v1[1];
        hv[6] = (_Float16)v1[2]; hv[7] = (_Float16)v1[3];
        *(half8*)(&sA[0][r * SA + off]) = hv;
    }
    __syncthreads();

    float4v acc[2][2];

    // ---- encoder: e = relu(obs @ encW^T + enc_b) -> sA[1]
    zero22(acc);
    gemm_tile<4>(&sA[0][0], prep + ENC_OFF, 16, ntl0, encW, DIN, use_prep, lane, acc);
    #pragma unroll
    for (int nn = 0; nn < 2; nn++) {
        int col = (ntl0 + nn) * 16 + l16;
        float bb = enc_b[col];
        #pragma unroll
        for (int mt = 0; mt < 2; mt++)
            #pragma unroll
            for (int r = 0; r < 4; r++) {
                int row = mt * 16 + quad * 4 + r;
                float v = acc[mt][nn][r] + bb;
                sA[1][row * SA + col] = (_Float16)fmaxf(v, 0.f);
            }
    }
    __syncthreads();

    // ---- fobs: h = e @ fobsW^T + fobs_b -> sA[0]
    zero22(acc);
    gemm_tile<8>(&sA[1][0], prep + FOBS_OFF, 16, ntl0, fobsW, HID, use_prep, lane, acc);
    #pragma unroll
    for (int nn = 0; nn < 2; nn++) {
        int col = (ntl0 + nn) * 16 + l16;
        float bb = fobs_b[col];
        #pragma unroll
        for (int mt = 0; mt < 2; mt++)
            #pragma unroll
            for (int r = 0; r < 4; r++) {
                int row = mt * 16 + quad * 4 + r;
                sA[0][row * SA + col] = (_Float16)(acc[mt][nn][r] + bb);
            }
    }
    __syncthreads();

    // ---- GRU1 fused (x=0 so gi = b_ih). A = sA[0] (h). One K-pass, 3 gate accs.
    {
        float4v aR[2][2], aZ[2][2], aN[2][2];
        zero22(aR); zero22(aZ); zero22(aN);
        #pragma unroll 2
        for (int ks = 0; ks < 8; ks++) {
            const int kbase = ks * 32 + kq;
            half8 a0 = *(const half8*)(&sA[0][l16 * SA + kbase]);
            half8 a1 = *(const half8*)(&sA[0][(16 + l16) * SA + kbase]);
            half8 bR0 = ldB(prep + WHH_OFF, 48,  0 + ntl0,     ks, whh, HID, use_prep, lane);
            half8 bR1 = ldB(prep + WHH_OFF, 48,  0 + ntl0 + 1, ks, whh, HID, use_prep, lane);
            half8 bZ0 = ldB(prep + WHH_OFF, 48, 16 + ntl0,     ks, whh, HID, use_prep, lane);
            half8 bZ1 = ldB(prep + WHH_OFF, 48, 16 + ntl0 + 1, ks, whh, HID, use_prep, lane);
            half8 bN0 = ldB(prep + WHH_OFF, 48, 32 + ntl0,     ks, whh, HID, use_prep, lane);
            half8 bN1 = ldB(prep + WHH_OFF, 48, 32 + ntl0 + 1, ks, whh, HID, use_prep, lane);
            aR[0][0] = __builtin_amdgcn_mfma_f32_16x16x32_f16(a0, bR0, aR[0][0], 0, 0, 0);
            aR[0][1] = __builtin_amdgcn_mfma_f32_16x16x32_f16(a0, bR1, aR[0][1], 0, 0, 0);
            aR[1][0] = __builtin_amdgcn_mfma_f32_16x16x32_f16(a1, bR0, aR[1][0], 0, 0, 0);
            aR[1][1] = __builtin_amdgcn_mfma_f32_16x16x32_f16(a1, bR1, aR[1][1], 0, 0, 0);
            aZ[0][0] = __builtin_amdgcn_mfma_f32_16x16x32_f16(a0, bZ0, aZ[0][0], 0, 0, 0);
            aZ[0][1] = __builtin_amdgcn_mfma_f32_16x16x32_f16(a0, bZ1, aZ[0][1], 0, 0, 0);
            aZ[1][0] = __builtin_amdgcn_mfma_f32_16x16x32_f16(a1, bZ0, aZ[1][0], 0, 0, 0);
            aZ[1][1] = __builtin_amdgcn_mfma_f32_16x16x32_f16(a1, bZ1, aZ[1][1], 0, 0, 0);
            aN[0][0] = __builtin_amdgcn_mfma_f32_16x16x32_f16(a0, bN0, aN[0][0], 0, 0, 0);
            aN[0][1] = __builtin_amdgcn_mfma_f32_16x16x32_f16(a0, bN1, aN[0][1], 0, 0, 0);
            aN[1][0] = __builtin_amdgcn_mfma_f32_16x16x32_f16(a1, bN0, aN[1][0], 0, 0, 0);
            aN[1][1] = __builtin_amdgcn_mfma_f32_16x16x32_f16(a1, bN1, aN[1][1], 0, 0, 0);
        }
        #pragma unroll
        for (int nn = 0; nn < 2; nn++) {
            int col = (ntl0 + nn) * 16 + l16;
            float biR = b_ih[col],       bhR = b_hh[col];
            float biZ = b_ih[256 + col], bhZ = b_hh[256 + col];
            float biN = b_ih[512 + col], bhN = b_hh[512 + col];
            float ssum = 0.f;
            #pragma unroll
            for (int mt = 0; mt < 2; mt++)
                #pragma unroll
                for (int r = 0; r < 4; r++) {
                    int row = mt * 16 + quad * 4 + r;
                    float rg = sigmoid_f(biR + aR[mt][nn][r] + bhR);
                    float zg = sigmoid_f(biZ + aZ[mt][nn][r] + bhZ);
                    float ng = tanh_f(biN + rg * (aN[mt][nn][r] + bhN));
                    float hold = (float)sA[0][row * SA + col];
                    float h1 = (1.f - zg) * ng + zg * hold;
                    sA[1][row * SA + col] = (_Float16)h1;   // h1 -> sA[1]
                    ssum += h1;
                }
            // column sum across the 4 quads (rows 0..31) -> S[col], no atomics
            ssum += __shfl_xor(ssum, 16);
            ssum += __shfl_xor(ssum, 32);
            if (lane < 16) S[col] = ssum;
        }
    }
    __syncthreads();

    // ---- comm: c = (colsum - h1)/32 -> sA[0] (fobs h is dead), vectorized half8
    for (int i = tid; i < (NA * HID) / 8; i += 512) {
        int r  = i >> 5;           // 32 chunks per 256-wide row
        int c8 = (i & 31) << 3;
        half8 hv = *(const half8*)(&sA[1][r * SA + c8]);
        float4v s0 = *(const float4v*)(&S[c8]);
        float4v s1 = *(const float4v*)(&S[c8 + 4]);
        half8 cv;
        cv[0] = (_Float16)((s0[0] - (float)hv[0]) * (1.f / 32.f));
        cv[1] = (_Float16)((s0[1] - (float)hv[1]) * (1.f / 32.f));
        cv[2] = (_Float16)((s0[2] - (float)hv[2]) * (1.f / 32.f));
        cv[3] = (_Float16)((s0[3] - (float)hv[3]) * (1.f / 32.f));
        cv[4] = (_Float16)((s1[0] - (float)hv[4]) * (1.f / 32.f));
        cv[5] = (_Float16)((s1[1] - (float)hv[5]) * (1.f / 32.f));
        cv[6] = (_Float16)((s1[2] - (float)hv[6]) * (1.f / 32.f));
        cv[7] = (_Float16)((s1[3] - (float)hv[7]) * (1.f / 32.f));
        *(half8*)(&sA[0][r * SA + c8]) = cv;
    }
    __syncthreads();
    if (tid < NA) S[tid] = 0.f;   // reuse S[0..31] as decoder row accumulators
    __syncthreads();

    // ---- GRU2 fused: gi from c (sA[0]) @ W_ih, gh from h1 (sA[1]) @ W_hh.
    // r,z gates share accumulators (sigmoid of gi+gh); n needs both halves.
    {
        float4v aR[2][2], aZ[2][2], aNi[2][2], aNh[2][2];
        zero22(aR); zero22(aZ); zero22(aNi); zero22(aNh);
        #pragma unroll 2
        for (int ks = 0; ks < 8; ks++) {
            const int kbase = ks * 32 + kq;
            // gi side
            half8 c0 = *(const half8*)(&sA[0][l16 * SA + kbase]);
            half8 c1 = *(const half8*)(&sA[0][(16 + l16) * SA + kbase]);
            half8 bIR0 = ldB(prep + WIH_OFF, 48,  0 + ntl0,     ks, wih, HID, use_prep, lane);
            half8 bIR1 = ldB(prep + WIH_OFF, 48,  0 + ntl0 + 1, ks, wih, HID, use_prep, lane);
            half8 bIZ0 = ldB(prep + WIH_OFF, 48, 16 + ntl0,     ks, wih, HID, use_prep, lane);
            half8 bIZ1 = ldB(prep + WIH_OFF, 48, 16 + ntl0 + 1, ks, wih, HID, use_prep, lane);
            half8 bIN0 = ldB(prep + WIH_OFF, 48, 32 + ntl0,     ks, wih, HID, use_prep, lane);
            half8 bIN1 = ldB(prep + WIH_OFF, 48, 32 + ntl0 + 1, ks, wih, HID, use_prep, lane);
            aR[0][0]  = __builtin_amdgcn_mfma_f32_16x16x32_f16(c0, bIR0, aR[0][0], 0, 0, 0);
            aR[0][1]  = __builtin_amdgcn_mfma_f32_16x16x32_f16(c0, bIR1, aR[0][1], 0, 0, 0);
            aR[1][0]  = __builtin_amdgcn_mfma_f32_16x16x32_f16(c1, bIR0, aR[1][0], 0, 0, 0);
            aR[1][1]  = __builtin_amdgcn_mfma_f32_16x16x32_f16(c1, bIR1, aR[1][1], 0, 0, 0);
            aZ[0][0]  = __builtin_amdgcn_mfma_f32_16x16x32_f16(c0, bIZ0, aZ[0][0], 0, 0, 0);
            aZ[0][1]  = __builtin_amdgcn_mfma_f32_16x16x32_f16(c0, bIZ1, aZ[0][1], 0, 0, 0);
            aZ[1][0]  = __builtin_amdgcn_mfma_f32_16x16x32_f16(c1, bIZ0, aZ[1][0], 0, 0, 0);
            aZ[1][1]  = __builtin_amdgcn_mfma_f32_16x16x32_f16(c1, bIZ1, aZ[1][1], 0, 0, 0);
            aNi[0][0] = __builtin_amdgcn_mfma_f32_16x16x32_f16(c0, bIN0, aNi[0][0], 0, 0, 0);
            aNi[0][1] = __builtin_amdgcn_mfma_f32_16x16x32_f16(c0, bIN1, aNi[0][1], 0, 0, 0);
            aNi[1][0] = __builtin_amdgcn_mfma_f32_16x16x32_f16(c1, bIN0, aNi[1][0], 0, 0, 0);
            aNi[1][1] = __builtin_amdgcn_mfma_f32_16x16x32_f16(c1, bIN1, aNi[1][1], 0, 0, 0);
            // gh side
            half8 h0 = *(const half8*)(&sA[1][l16 * SA + kbase]);
            half8 h1f = *(const half8*)(&sA[1][(16 + l16) * SA + kbase]);
            half8 bHR0 = ldB(prep + WHH_OFF, 48,  0 + ntl0,     ks, whh, HID, use_prep, lane);
            half8 bHR1 = ldB(prep + WHH_OFF, 48,  0 + ntl0 + 1, ks, whh, HID, use_prep, lane);
            half8 bHZ0 = ldB(prep + WHH_OFF, 48, 16 + ntl0,     ks, whh, HID, use_prep, lane);
            half8 bHZ1 = ldB(prep + WHH_OFF, 48, 16 + ntl0 + 1, ks, whh, HID, use_prep, lane);
            half8 bHN0 = ldB(prep + WHH_OFF, 48, 32 + ntl0,     ks, whh, HID, use_prep, lane);
            half8 bHN1 = ldB(prep + WHH_OFF, 48, 32 + ntl0 + 1, ks, whh, HID, use_prep, lane);
            aR[0][0]  = __builtin_amdgcn_mfma_f32_16x16x32_f16(h0,  bHR0, aR[0][0], 0, 0, 0);
            aR[0][1]  = __builtin_amdgcn_mfma_f32_16x16x32_f16(h0,  bHR1, aR[0][1], 0, 0, 0);
            aR[1][0]  = __builtin_amdgcn_mfma_f32_16x16x32_f16(h1f, bHR0, aR[1][0], 0, 0, 0);
            aR[1][1]  = __builtin_amdgcn_mfma_f32_16x16x32_f16(h1f, bHR1, aR[1][1], 0, 0, 0);
            aZ[0][0]  = __builtin_amdgcn_mfma_f32_16x16x32_f16(h0,  bHZ0, aZ[0][0], 0, 0, 0);
            aZ[0][1]  = __builtin_amdgcn_mfma_f32_16x16x32_f16(h0,  bHZ1, aZ[0][1], 0, 0, 0);
            aZ[1][0]  = __builtin_amdgcn_mfma_f32_16x16x32_f16(h1f, bHZ0, aZ[1][0], 0, 0, 0);
            aZ[1][1]  = __builtin_amdgcn_mfma_f32_16x16x32_f16(h1f, bHZ1, aZ[1][1], 0, 0, 0);
            aNh[0][0] = __builtin_amdgcn_mfma_f32_16x16x32_f16(h0,  bHN0, aNh[0][0], 0, 0, 0);
            aNh[0][1] = __builtin_amdgcn_mfma_f32_16x16x32_f16(h0,  bHN1, aNh[0][1], 0, 0, 0);
            aNh[1][0] = __builtin_amdgcn_mfma_f32_16x16x32_f16(h1f, bHN0, aNh[1][0], 0, 0, 0);
            aNh[1][1] = __builtin_amdgcn_mfma_f32_16x16x32_f16(h1f, bHN1, aNh[1][1], 0, 0, 0);
        }

        // ---- epilogue + decoder fold: out[row] = sum_col h2*dec_W[col] + dec_b
        float dw0 = dec_W[(ntl0    ) * 16 + l16];
        float dw1 = dec_W[(ntl0 + 1) * 16 + l16];
        float p[2][4];
        #pragma unroll
        for (int mt = 0; mt < 2; mt++)
            #pragma unroll
            for (int r = 0; r < 4; r++)
                p[mt][r] = 0.f;
        #pragma unroll
        for (int nn = 0; nn < 2; nn++) {
            int col = (ntl0 + nn) * 16 + l16;
            float biR = b_ih[col],       bhR = b_hh[col];
            float biZ = b_ih[256 + col], bhZ = b_hh[256 + col];
            float biN = b_ih[512 + col], bhN = b_hh[512 + col];
            float dw = nn ? dw1 : dw0;
            #pragma unroll
            for (int mt = 0; mt < 2; mt++)
                #pragma unroll
                for (int r = 0; r < 4; r++) {
                    int row = mt * 16 + quad * 4 + r;
                    float rg = sigmoid_f(aR[mt][nn][r] + biR + bhR);
                    float zg = sigmoid_f(aZ[mt][nn][r] + biZ + bhZ);
                    float ng = tanh_f((aNi[mt][nn][r] + biN) + rg * (aNh[mt][nn][r] + bhN));
                    float h1v = (float)sA[1][row * SA + col];
                    float h2 = (1.f - zg) * ng + zg * h1v;
                    p[mt][r] += h2 * dw;
                }
        }
        #pragma unroll
        for (int m = 1; m <= 8; m <<= 1) {
            #pragma unroll
            for (int mt = 0; mt < 2; mt++)
                #pragma unroll
                for (int r = 0; r < 4; r++)
                    p[mt][r] += __shfl_xor(p[mt][r], m);
        }
        if (l16 == 0) {
            #pragma unroll
            for (int mt = 0; mt < 2; mt++)
                #pragma unroll
                for (int r = 0; r < 4; r++)
                    atomicAdd(&S[mt * 16 + quad * 4 + r], p[mt][r]);
        }
    }
    __syncthreads();
    if (tid < NA) out[(size_t)b * NA + tid] = S[tid] + dec_b[0];
}

extern "C" void kernel_launch(void* const* d_in, const int* in_sizes, int n_in,
                              void* d_out, int out_size, void* d_ws, size_t ws_size,
                              hipStream_t stream) {
    const float* obs   = (const float*)d_in[0];
    // d_in[1] (act) is unused by the reference
    const float* encW  = (const float*)d_in[2];
    const float* encb  = (const float*)d_in[3];
    const float* fobsW = (const float*)d_in[4];
    const float* fobsb = (const float*)d_in[5];
    const float* wih   = (const float*)d_in[6];
    const float* bih   = (const float*)d_in[7];
    const float* whh   = (const float*)d_in[8];
    const float* bhh   = (const float*)d_in[9];
    const float* decW  = (const float*)d_in[10];
    const float* decb  = (const float*)d_in[11];
    float* out = (float*)d_out;

    _Float16* prep = (_Float16*)d_ws;
    int use_prep = (ws_size >= (size_t)PREP_TOTAL * sizeof(_Float16)) ? 1 : 0;
    if (use_prep) {
        prep_weights<<<(PREP_TOTAL + 255) / 256, 256, 0, stream>>>(encW, fobsW, wih, whh, prep);
    }
    commnet_fused<<<NB, 512, 0, stream>>>(obs, prep, encb, fobsb, bih, bhh, decW, decb, out,
                                          encW, fobsW, wih, whh, use_prep);
}

// Round 2
// 247.847 us; speedup vs baseline: 1.1116x; 1.1116x over previous
//
#include <hip/hip_runtime.h>
#include <hip/hip_fp16.h>

// CommNet critic forward, fully fused: 1 workgroup = 2 batches (64 agent-rows).
// All GEMMs via v_mfma_f32_16x16x32_f16 (fp32 accumulate). B=2048,A=32,D=128,H=256.
// V3: 2 batches/block (halves L2 weight traffic, 2x MFMA per B-load),
//     1024 threads = 16 waves, 1 col-tile (16 cols) per wave per gate.

#define NB   2048
#define NA   32
#define DIN  128
#define HID  256
#define SA   264   // f16 row stride for activation LDS tiles (stride 528B -> 2-way-free bank spread)
#define MROWS 64   // 2 batches x 32 agents

typedef _Float16 half8  __attribute__((ext_vector_type(8)));
typedef float    float4v __attribute__((ext_vector_type(4)));

// f16 weight-fragment arena layout in d_ws (element offsets)
#define ENC_OFF    0
#define FOBS_OFF   32768
#define WIH_OFF    98304
#define WHH_OFF    294912
#define PREP_TOTAL 491520   // f16 elements -> 983040 bytes needed in ws

// Pre-arrange weights into exact MFMA B-fragment order, f16:
// frag[((ks*NT + nt)*64 + lane)*8 + j] = W[nt*16 + lane%16][ks*32 + (lane/16)*8 + j]
__global__ void prep_weights(const float* __restrict__ encW, const float* __restrict__ fobsW,
                             const float* __restrict__ wih,  const float* __restrict__ whh,
                             _Float16* __restrict__ prep) {
    int F = blockIdx.x * 256 + threadIdx.x;
    if (F >= PREP_TOTAL) return;
    const float* src; int K, NT, local = F;
    if (F < FOBS_OFF)     { src = encW;  K = 128; NT = 16; }
    else if (F < WIH_OFF) { src = fobsW; K = 256; NT = 16; local = F - FOBS_OFF; }
    else if (F < WHH_OFF) { src = wih;   K = 256; NT = 48; local = F - WIH_OFF; }
    else                  { src = whh;   K = 256; NT = 48; local = F - WHH_OFF; }
    int j    = local & 7;
    int lane = (local >> 3) & 63;
    int t    = local >> 9;
    int nt   = t % NT;
    int ks   = t / NT;
    int col  = nt * 16 + (lane & 15);
    int k    = ks * 32 + ((lane >> 4) << 3) + j;
    prep[F] = (_Float16)src[col * K + k];
}

__device__ __forceinline__ float sigmoid_f(float x) {
    x = fminf(fmaxf(x, -30.f), 30.f);
    return 1.f / (1.f + __expf(-x));
}
__device__ __forceinline__ float tanh_f(float x) {
    x = fminf(fmaxf(x, -15.f), 15.f);
    float e = __expf(-2.f * x);
    return (1.f - e) / (1.f + e);
}

// Load one MFMA B-fragment (16 cols x 32 k) either from prepped arena or raw fp32.
__device__ __forceinline__ half8 ldB(const _Float16* __restrict__ prepm, int NT, int nt, int ks,
                                     const float* __restrict__ raw, int K, int use_prep, int lane) {
    if (use_prep)
        return *(const half8*)(prepm + (((ks * NT + nt) * 64 + lane) << 3));
    half8 b;
    int l16 = lane & 15, kq = (lane >> 4) << 3;
    #pragma unroll
    for (int j = 0; j < 8; j++)
        b[j] = (_Float16)raw[(nt * 16 + l16) * K + ks * 32 + kq + j];
    return b;
}

// One wave computes 64 rows x 16 cols (mt=0..3, single ntile) of a GEMM.
template<int KSTEPS>
__device__ __forceinline__ void gemm_col16(const _Float16* __restrict__ Abuf,
        const _Float16* __restrict__ prepm, int NT, int nt,
        const float* __restrict__ raw, int K, int use_prep,
        int lane, float4v acc[4])
{
    const int l16 = lane & 15;
    const int kq  = (lane >> 4) << 3;
    #pragma unroll 2
    for (int ks = 0; ks < KSTEPS; ks++) {
        int kbase = ks * 32 + kq;
        half8 Af[4];
        #pragma unroll
        for (int mt = 0; mt < 4; mt++)
            Af[mt] = *(const half8*)(Abuf + (mt * 16 + l16) * SA + kbase);
        half8 b0 = ldB(prepm, NT, nt, ks, raw, K, use_prep, lane);
        #pragma unroll
        for (int mt = 0; mt < 4; mt++)
            acc[mt] = __builtin_amdgcn_mfma_f32_16x16x32_f16(Af[mt], b0, acc[mt], 0, 0, 0);
    }
}

__global__ __launch_bounds__(1024) void commnet_fused(
    const float* __restrict__ obs, const _Float16* __restrict__ prep,
    const float* __restrict__ enc_b, const float* __restrict__ fobs_b,
    const float* __restrict__ b_ih, const float* __restrict__ b_hh,
    const float* __restrict__ dec_W, const float* __restrict__ dec_b,
    float* __restrict__ out,
    const float* __restrict__ encW, const float* __restrict__ fobsW,
    const float* __restrict__ wih, const float* __restrict__ whh,
    int use_prep)
{
    const int b    = blockIdx.x;       // block handles batches 2b, 2b+1 (rows 0..63)
    const int tid  = threadIdx.x;
    const int lane = tid & 63;
    const int w    = tid >> 6;         // wave 0..15 -> col tile w (cols 16w..16w+15)
    const int l16  = lane & 15;
    const int quad = lane >> 4;
    const int kq   = quad << 3;
    const int col  = w * 16 + l16;     // this lane's output column (fixed all phases)

    __shared__ __align__(16) _Float16 sA[2][MROWS * SA];
    __shared__ __align__(16) float S[2][HID];   // per-batch column sums of h1
    __shared__ float Srow[MROWS];               // decoder row accumulators

    // ---- stage obs (fp32 global -> f16 LDS): 64 rows x 128, one half8 per thread
    {
        const float* obsb = obs + (size_t)b * MROWS * DIN;
        int r   = tid >> 4;            // 16 chunks per 128-wide row, 64 rows
        int off = (tid & 15) << 3;
        const float* src = obsb + r * DIN + off;
        float4v v0 = *(const float4v*)(src);
        float4v v1 = *(const float4v*)(src + 4);
        half8 hv;
        hv[0] = (_Float16)v0[0]; hv[1] = (_Float16)v0[1];
        hv[2] = (_Float16)v0[2]; hv[3] = (_Float16)v0[3];
        hv[4] = (_Float16)v1[0]; hv[5] = (_Float16)v1[1];
        hv[6] = (_Float16)v1[2]; hv[7] = (_Float16)v1[3];
        *(half8*)(&sA[0][r * SA + off]) = hv;
    }
    __syncthreads();

    float4v acc[4];

    // ---- encoder: e = relu(obs @ encW^T + enc_b) : T0 -> T1
    {
        float4v z = {0.f, 0.f, 0.f, 0.f};
        acc[0] = z; acc[1] = z; acc[2] = z; acc[3] = z;
        gemm_col16<4>(&sA[0][0], prep + ENC_OFF, 16, w, encW, DIN, use_prep, lane, acc);
        float bb = enc_b[col];
        #pragma unroll
        for (int mt = 0; mt < 4; mt++)
            #pragma unroll
            for (int r = 0; r < 4; r++) {
                int row = mt * 16 + quad * 4 + r;
                sA[1][row * SA + col] = (_Float16)fmaxf(acc[mt][r] + bb, 0.f);
            }
    }
    __syncthreads();

    // ---- fobs: h = e @ fobsW^T + fobs_b : T1 -> T0
    {
        float4v z = {0.f, 0.f, 0.f, 0.f};
        acc[0] = z; acc[1] = z; acc[2] = z; acc[3] = z;
        gemm_col16<8>(&sA[1][0], prep + FOBS_OFF, 16, w, fobsW, HID, use_prep, lane, acc);
        float bb = fobs_b[col];
        #pragma unroll
        for (int mt = 0; mt < 4; mt++)
            #pragma unroll
            for (int r = 0; r < 4; r++) {
                int row = mt * 16 + quad * 4 + r;
                sA[0][row * SA + col] = (_Float16)(acc[mt][r] + bb);
            }
    }
    __syncthreads();

    // ---- GRU1 fused (x=0 so gi = b_ih). A = T0 (h). One K-pass, 3 gate acc sets.
    {
        float4v aR[4], aZ[4], aN[4];
        float4v z = {0.f, 0.f, 0.f, 0.f};
        #pragma unroll
        for (int mt = 0; mt < 4; mt++) { aR[mt] = z; aZ[mt] = z; aN[mt] = z; }
        #pragma unroll 2
        for (int ks = 0; ks < 8; ks++) {
            const int kbase = ks * 32 + kq;
            half8 Af[4];
            #pragma unroll
            for (int mt = 0; mt < 4; mt++)
                Af[mt] = *(const half8*)(&sA[0][(mt * 16 + l16) * SA + kbase]);
            half8 bR = ldB(prep + WHH_OFF, 48,  0 + w, ks, whh, HID, use_prep, lane);
            half8 bZ = ldB(prep + WHH_OFF, 48, 16 + w, ks, whh, HID, use_prep, lane);
            half8 bN = ldB(prep + WHH_OFF, 48, 32 + w, ks, whh, HID, use_prep, lane);
            #pragma unroll
            for (int mt = 0; mt < 4; mt++)
                aR[mt] = __builtin_amdgcn_mfma_f32_16x16x32_f16(Af[mt], bR, aR[mt], 0, 0, 0);
            #pragma unroll
            for (int mt = 0; mt < 4; mt++)
                aZ[mt] = __builtin_amdgcn_mfma_f32_16x16x32_f16(Af[mt], bZ, aZ[mt], 0, 0, 0);
            #pragma unroll
            for (int mt = 0; mt < 4; mt++)
                aN[mt] = __builtin_amdgcn_mfma_f32_16x16x32_f16(Af[mt], bN, aN[mt], 0, 0, 0);
        }
        float biR = b_ih[col],       bhR = b_hh[col];
        float biZ = b_ih[256 + col], bhZ = b_hh[256 + col];
        float biN = b_ih[512 + col], bhN = b_hh[512 + col];
        float s0 = 0.f, s1 = 0.f;
        #pragma unroll
        for (int mt = 0; mt < 4; mt++) {
            float psum = 0.f;
            #pragma unroll
            for (int r = 0; r < 4; r++) {
                int row = mt * 16 + quad * 4 + r;
                float rg = sigmoid_f(biR + aR[mt][r] + bhR);
                float zg = sigmoid_f(biZ + aZ[mt][r] + bhZ);
                float ng = tanh_f(biN + rg * (aN[mt][r] + bhN));
                float hold = (float)sA[0][row * SA + col];
                float h1 = (1.f - zg) * ng + zg * hold;
                sA[1][row * SA + col] = (_Float16)h1;   // h1 -> T1
                psum += h1;
            }
            if (mt < 2) s0 += psum; else s1 += psum;
        }
        // column sums across the 4 quads (rows within each batch) -> S, no atomics
        s0 += __shfl_xor(s0, 16); s0 += __shfl_xor(s0, 32);
        s1 += __shfl_xor(s1, 16); s1 += __shfl_xor(s1, 32);
        if (lane < 16) { S[0][col] = s0; S[1][col] = s1; }
    }
    __syncthreads();

    // ---- comm: c = (colsum - h1)/32 : T1 -> T0 (per-batch colsum), vectorized half8
    {
        #pragma unroll
        for (int it = 0; it < 2; it++) {
            int i  = tid + it * 1024;       // 2048 chunks total
            int r  = i >> 5;                // row 0..63
            int c8 = (i & 31) << 3;
            const float* Sp = &S[r >> 5][0];
            half8 hv = *(const half8*)(&sA[1][r * SA + c8]);
            float4v t0 = *(const float4v*)(Sp + c8);
            float4v t1 = *(const float4v*)(Sp + c8 + 4);
            half8 cv;
            cv[0] = (_Float16)((t0[0] - (float)hv[0]) * (1.f / 32.f));
            cv[1] = (_Float16)((t0[1] - (float)hv[1]) * (1.f / 32.f));
            cv[2] = (_Float16)((t0[2] - (float)hv[2]) * (1.f / 32.f));
            cv[3] = (_Float16)((t0[3] - (float)hv[3]) * (1.f / 32.f));
            cv[4] = (_Float16)((t1[0] - (float)hv[4]) * (1.f / 32.f));
            cv[5] = (_Float16)((t1[1] - (float)hv[5]) * (1.f / 32.f));
            cv[6] = (_Float16)((t1[2] - (float)hv[6]) * (1.f / 32.f));
            cv[7] = (_Float16)((t1[3] - (float)hv[7]) * (1.f / 32.f));
            *(half8*)(&sA[0][r * SA + c8]) = cv;
        }
        if (tid < MROWS) Srow[tid] = 0.f;   // decoder row accumulators
    }
    __syncthreads();

    // ---- GRU2 fused: gi from c (T0) @ W_ih, gh from h1 (T1) @ W_hh.
    // r,z gates share accumulators (sigmoid of gi+gh); n needs both halves.
    {
        float4v aR[4], aZ[4], aNi[4], aNh[4];
        float4v z = {0.f, 0.f, 0.f, 0.f};
        #pragma unroll
        for (int mt = 0; mt < 4; mt++) { aR[mt] = z; aZ[mt] = z; aNi[mt] = z; aNh[mt] = z; }
        #pragma unroll 2
        for (int ks = 0; ks < 8; ks++) {
            const int kbase = ks * 32 + kq;
            // gi side: A = c
            {
                half8 Cf[4];
                #pragma unroll
                for (int mt = 0; mt < 4; mt++)
                    Cf[mt] = *(const half8*)(&sA[0][(mt * 16 + l16) * SA + kbase]);
                half8 bR = ldB(prep + WIH_OFF, 48,  0 + w, ks, wih, HID, use_prep, lane);
                half8 bZ = ldB(prep + WIH_OFF, 48, 16 + w, ks, wih, HID, use_prep, lane);
                half8 bN = ldB(prep + WIH_OFF, 48, 32 + w, ks, wih, HID, use_prep, lane);
                #pragma unroll
                for (int mt = 0; mt < 4; mt++)
                    aR[mt]  = __builtin_amdgcn_mfma_f32_16x16x32_f16(Cf[mt], bR, aR[mt], 0, 0, 0);
                #pragma unroll
                for (int mt = 0; mt < 4; mt++)
                    aZ[mt]  = __builtin_amdgcn_mfma_f32_16x16x32_f16(Cf[mt], bZ, aZ[mt], 0, 0, 0);
                #pragma unroll
                for (int mt = 0; mt < 4; mt++)
                    aNi[mt] = __builtin_amdgcn_mfma_f32_16x16x32_f16(Cf[mt], bN, aNi[mt], 0, 0, 0);
            }
            // gh side: A = h1
            {
                half8 Hf[4];
                #pragma unroll
                for (int mt = 0; mt < 4; mt++)
                    Hf[mt] = *(const half8*)(&sA[1][(mt * 16 + l16) * SA + kbase]);
                half8 bR = ldB(prep + WHH_OFF, 48,  0 + w, ks, whh, HID, use_prep, lane);
                half8 bZ = ldB(prep + WHH_OFF, 48, 16 + w, ks, whh, HID, use_prep, lane);
                half8 bN = ldB(prep + WHH_OFF, 48, 32 + w, ks, whh, HID, use_prep, lane);
                #pragma unroll
                for (int mt = 0; mt < 4; mt++)
                    aR[mt]  = __builtin_amdgcn_mfma_f32_16x16x32_f16(Hf[mt], bR, aR[mt], 0, 0, 0);
                #pragma unroll
                for (int mt = 0; mt < 4; mt++)
                    aZ[mt]  = __builtin_amdgcn_mfma_f32_16x16x32_f16(Hf[mt], bZ, aZ[mt], 0, 0, 0);
                #pragma unroll
                for (int mt = 0; mt < 4; mt++)
                    aNh[mt] = __builtin_amdgcn_mfma_f32_16x16x32_f16(Hf[mt], bN, aNh[mt], 0, 0, 0);
            }
        }

        // ---- epilogue + decoder fold: out[row] = sum_col h2*dec_W[col] + dec_b
        float biR = b_ih[col],       bhR = b_hh[col];
        float biZ = b_ih[256 + col], bhZ = b_hh[256 + col];
        float biN = b_ih[512 + col], bhN = b_hh[512 + col];
        float dw  = dec_W[col];
        float p[4][4];
        #pragma unroll
        for (int mt = 0; mt < 4; mt++)
            #pragma unroll
            for (int r = 0; r < 4; r++) {
                int row = mt * 16 + quad * 4 + r;
                float rg = sigmoid_f(aR[mt][r] + biR + bhR);
                float zg = sigmoid_f(aZ[mt][r] + biZ + bhZ);
                float ng = tanh_f((aNi[mt][r] + biN) + rg * (aNh[mt][r] + bhN));
                float h1v = (float)sA[1][row * SA + col];
                float h2 = (1.f - zg) * ng + zg * h1v;
                p[mt][r] = h2 * dw;
            }
        #pragma unroll
        for (int m = 1; m <= 8; m <<= 1) {
            #pragma unroll
            for (int mt = 0; mt < 4; mt++)
                #pragma unroll
                for (int r = 0; r < 4; r++)
                    p[mt][r] += __shfl_xor(p[mt][r], m);
        }
        if (l16 == 0) {
            #pragma unroll
            for (int mt = 0; mt < 4; mt++)
                #pragma unroll
                for (int r = 0; r < 4; r++)
                    atomicAdd(&Srow[mt * 16 + quad * 4 + r], p[mt][r]);
        }
    }
    __syncthreads();
    if (tid < MROWS) out[(size_t)b * MROWS + tid] = Srow[tid] + dec_b[0];
}

extern "C" void kernel_launch(void* const* d_in, const int* in_sizes, int n_in,
                              void* d_out, int out_size, void* d_ws, size_t ws_size,
                              hipStream_t stream) {
    const float* obs   = (const float*)d_in[0];
    // d_in[1] (act) is unused by the reference
    const float* encW  = (const float*)d_in[2];
    const float* encb  = (const float*)d_in[3];
    const float* fobsW = (const float*)d_in[4];
    const float* fobsb = (const float*)d_in[5];
    const float* wih   = (const float*)d_in[6];
    const float* bih   = (const float*)d_in[7];
    const float* whh   = (const float*)d_in[8];
    const float* bhh   = (const float*)d_in[9];
    const float* decW  = (const float*)d_in[10];
    const float* decb  = (const float*)d_in[11];
    float* out = (float*)d_out;

    _Float16* prep = (_Float16*)d_ws;
    int use_prep = (ws_size >= (size_t)PREP_TOTAL * sizeof(_Float16)) ? 1 : 0;
    if (use_prep) {
        prep_weights<<<(PREP_TOTAL + 255) / 256, 256, 0, stream>>>(encW, fobsW, wih, whh, prep);
    }
    commnet_fused<<<NB / 2, 1024, 0, stream>>>(obs, prep, encb, fobsb, bih, bhh, decW, decb, out,
                                               encW, fobsW, wih, whh, use_prep);
}

// Round 3
// 245.697 us; speedup vs baseline: 1.1213x; 1.0088x over previous
//
#include <hip/hip_runtime.h>
#include <hip/hip_fp16.h>

// CommNet critic forward, fully fused: 1 workgroup = 2 batches (64 agent-rows).
// All GEMMs via v_mfma_f32_16x16x32_f16 (fp32 accumulate). B=2048,A=32,D=128,H=256.
// V4: __launch_bounds__(1024, 4) -> 128-VGPR budget. V3's default budget was 64 VGPR,
//     which spilled the GRU accumulators (WRITE_SIZE=123MB of scratch traffic).
//     16 waves/CU (50% occ) with no spills beats 64-VGPR + scratch round-trips.

#define NB   2048
#define NA   32
#define DIN  128
#define HID  256
#define SA   264   // f16 row stride for activation LDS tiles (stride 528B -> even bank spread)
#define MROWS 64   // 2 batches x 32 agents

typedef _Float16 half8  __attribute__((ext_vector_type(8)));
typedef float    float4v __attribute__((ext_vector_type(4)));

// f16 weight-fragment arena layout in d_ws (element offsets)
#define ENC_OFF    0
#define FOBS_OFF   32768
#define WIH_OFF    98304
#define WHH_OFF    294912
#define PREP_TOTAL 491520   // f16 elements -> 983040 bytes needed in ws

// Pre-arrange weights into exact MFMA B-fragment order, f16:
// frag[((ks*NT + nt)*64 + lane)*8 + j] = W[nt*16 + lane%16][ks*32 + (lane/16)*8 + j]
__global__ void prep_weights(const float* __restrict__ encW, const float* __restrict__ fobsW,
                             const float* __restrict__ wih,  const float* __restrict__ whh,
                             _Float16* __restrict__ prep) {
    int F = blockIdx.x * 256 + threadIdx.x;
    if (F >= PREP_TOTAL) return;
    const float* src; int K, NT, local = F;
    if (F < FOBS_OFF)     { src = encW;  K = 128; NT = 16; }
    else if (F < WIH_OFF) { src = fobsW; K = 256; NT = 16; local = F - FOBS_OFF; }
    else if (F < WHH_OFF) { src = wih;   K = 256; NT = 48; local = F - WIH_OFF; }
    else                  { src = whh;   K = 256; NT = 48; local = F - WHH_OFF; }
    int j    = local & 7;
    int lane = (local >> 3) & 63;
    int t    = local >> 9;
    int nt   = t % NT;
    int ks   = t / NT;
    int col  = nt * 16 + (lane & 15);
    int k    = ks * 32 + ((lane >> 4) << 3) + j;
    prep[F] = (_Float16)src[col * K + k];
}

__device__ __forceinline__ float sigmoid_f(float x) {
    x = fminf(fmaxf(x, -30.f), 30.f);
    return 1.f / (1.f + __expf(-x));
}
__device__ __forceinline__ float tanh_f(float x) {
    x = fminf(fmaxf(x, -15.f), 15.f);
    float e = __expf(-2.f * x);
    return (1.f - e) / (1.f + e);
}

// Load one MFMA B-fragment (16 cols x 32 k) either from prepped arena or raw fp32.
__device__ __forceinline__ half8 ldB(const _Float16* __restrict__ prepm, int NT, int nt, int ks,
                                     const float* __restrict__ raw, int K, int use_prep, int lane) {
    if (use_prep)
        return *(const half8*)(prepm + (((ks * NT + nt) * 64 + lane) << 3));
    half8 b;
    int l16 = lane & 15, kq = (lane >> 4) << 3;
    #pragma unroll
    for (int j = 0; j < 8; j++)
        b[j] = (_Float16)raw[(nt * 16 + l16) * K + ks * 32 + kq + j];
    return b;
}

// One wave computes 64 rows x 16 cols (mt=0..3, single ntile) of a GEMM.
template<int KSTEPS>
__device__ __forceinline__ void gemm_col16(const _Float16* __restrict__ Abuf,
        const _Float16* __restrict__ prepm, int NT, int nt,
        const float* __restrict__ raw, int K, int use_prep,
        int lane, float4v acc[4])
{
    const int l16 = lane & 15;
    const int kq  = (lane >> 4) << 3;
    #pragma unroll 2
    for (int ks = 0; ks < KSTEPS; ks++) {
        int kbase = ks * 32 + kq;
        half8 Af[4];
        #pragma unroll
        for (int mt = 0; mt < 4; mt++)
            Af[mt] = *(const half8*)(Abuf + (mt * 16 + l16) * SA + kbase);
        half8 b0 = ldB(prepm, NT, nt, ks, raw, K, use_prep, lane);
        #pragma unroll
        for (int mt = 0; mt < 4; mt++)
            acc[mt] = __builtin_amdgcn_mfma_f32_16x16x32_f16(Af[mt], b0, acc[mt], 0, 0, 0);
    }
}

__global__ __launch_bounds__(1024, 4) void commnet_fused(
    const float* __restrict__ obs, const _Float16* __restrict__ prep,
    const float* __restrict__ enc_b, const float* __restrict__ fobs_b,
    const float* __restrict__ b_ih, const float* __restrict__ b_hh,
    const float* __restrict__ dec_W, const float* __restrict__ dec_b,
    float* __restrict__ out,
    const float* __restrict__ encW, const float* __restrict__ fobsW,
    const float* __restrict__ wih, const float* __restrict__ whh,
    int use_prep)
{
    const int b    = blockIdx.x;       // block handles batches 2b, 2b+1 (rows 0..63)
    const int tid  = threadIdx.x;
    const int lane = tid & 63;
    const int w    = tid >> 6;         // wave 0..15 -> col tile w (cols 16w..16w+15)
    const int l16  = lane & 15;
    const int quad = lane >> 4;
    const int kq   = quad << 3;
    const int col  = w * 16 + l16;     // this lane's output column (fixed all phases)

    __shared__ __align__(16) _Float16 sA[2][MROWS * SA];
    __shared__ __align__(16) float S[2][HID];   // per-batch column sums of h1
    __shared__ float Srow[MROWS];               // decoder row accumulators

    // ---- stage obs (fp32 global -> f16 LDS): 64 rows x 128, one half8 per thread
    {
        const float* obsb = obs + (size_t)b * MROWS * DIN;
        int r   = tid >> 4;            // 16 chunks per 128-wide row, 64 rows
        int off = (tid & 15) << 3;
        const float* src = obsb + r * DIN + off;
        float4v v0 = *(const float4v*)(src);
        float4v v1 = *(const float4v*)(src + 4);
        half8 hv;
        hv[0] = (_Float16)v0[0]; hv[1] = (_Float16)v0[1];
        hv[2] = (_Float16)v0[2]; hv[3] = (_Float16)v0[3];
        hv[4] = (_Float16)v1[0]; hv[5] = (_Float16)v1[1];
        hv[6] = (_Float16)v1[2]; hv[7] = (_Float16)v1[3];
        *(half8*)(&sA[0][r * SA + off]) = hv;
    }
    __syncthreads();

    float4v acc[4];

    // ---- encoder: e = relu(obs @ encW^T + enc_b) : T0 -> T1
    {
        float4v z = {0.f, 0.f, 0.f, 0.f};
        acc[0] = z; acc[1] = z; acc[2] = z; acc[3] = z;
        gemm_col16<4>(&sA[0][0], prep + ENC_OFF, 16, w, encW, DIN, use_prep, lane, acc);
        float bb = enc_b[col];
        #pragma unroll
        for (int mt = 0; mt < 4; mt++)
            #pragma unroll
            for (int r = 0; r < 4; r++) {
                int row = mt * 16 + quad * 4 + r;
                sA[1][row * SA + col] = (_Float16)fmaxf(acc[mt][r] + bb, 0.f);
            }
    }
    __syncthreads();

    // ---- fobs: h = e @ fobsW^T + fobs_b : T1 -> T0
    {
        float4v z = {0.f, 0.f, 0.f, 0.f};
        acc[0] = z; acc[1] = z; acc[2] = z; acc[3] = z;
        gemm_col16<8>(&sA[1][0], prep + FOBS_OFF, 16, w, fobsW, HID, use_prep, lane, acc);
        float bb = fobs_b[col];
        #pragma unroll
        for (int mt = 0; mt < 4; mt++)
            #pragma unroll
            for (int r = 0; r < 4; r++) {
                int row = mt * 16 + quad * 4 + r;
                sA[0][row * SA + col] = (_Float16)(acc[mt][r] + bb);
            }
    }
    __syncthreads();

    // ---- GRU1 fused (x=0 so gi = b_ih). A = T0 (h). One K-pass, 3 gate acc sets.
    {
        float4v aR[4], aZ[4], aN[4];
        float4v z = {0.f, 0.f, 0.f, 0.f};
        #pragma unroll
        for (int mt = 0; mt < 4; mt++) { aR[mt] = z; aZ[mt] = z; aN[mt] = z; }
        #pragma unroll 2
        for (int ks = 0; ks < 8; ks++) {
            const int kbase = ks * 32 + kq;
            half8 Af[4];
            #pragma unroll
            for (int mt = 0; mt < 4; mt++)
                Af[mt] = *(const half8*)(&sA[0][(mt * 16 + l16) * SA + kbase]);
            half8 bR = ldB(prep + WHH_OFF, 48,  0 + w, ks, whh, HID, use_prep, lane);
            half8 bZ = ldB(prep + WHH_OFF, 48, 16 + w, ks, whh, HID, use_prep, lane);
            half8 bN = ldB(prep + WHH_OFF, 48, 32 + w, ks, whh, HID, use_prep, lane);
            #pragma unroll
            for (int mt = 0; mt < 4; mt++)
                aR[mt] = __builtin_amdgcn_mfma_f32_16x16x32_f16(Af[mt], bR, aR[mt], 0, 0, 0);
            #pragma unroll
            for (int mt = 0; mt < 4; mt++)
                aZ[mt] = __builtin_amdgcn_mfma_f32_16x16x32_f16(Af[mt], bZ, aZ[mt], 0, 0, 0);
            #pragma unroll
            for (int mt = 0; mt < 4; mt++)
                aN[mt] = __builtin_amdgcn_mfma_f32_16x16x32_f16(Af[mt], bN, aN[mt], 0, 0, 0);
        }
        float biR = b_ih[col],       bhR = b_hh[col];
        float biZ = b_ih[256 + col], bhZ = b_hh[256 + col];
        float biN = b_ih[512 + col], bhN = b_hh[512 + col];
        float s0 = 0.f, s1 = 0.f;
        #pragma unroll
        for (int mt = 0; mt < 4; mt++) {
            float psum = 0.f;
            #pragma unroll
            for (int r = 0; r < 4; r++) {
                int row = mt * 16 + quad * 4 + r;
                float rg = sigmoid_f(biR + aR[mt][r] + bhR);
                float zg = sigmoid_f(biZ + aZ[mt][r] + bhZ);
                float ng = tanh_f(biN + rg * (aN[mt][r] + bhN));
                float hold = (float)sA[0][row * SA + col];
                float h1 = (1.f - zg) * ng + zg * hold;
                sA[1][row * SA + col] = (_Float16)h1;   // h1 -> T1
                psum += h1;
            }
            if (mt < 2) s0 += psum; else s1 += psum;
        }
        // column sums across the 4 quads (rows within each batch) -> S, no atomics
        s0 += __shfl_xor(s0, 16); s0 += __shfl_xor(s0, 32);
        s1 += __shfl_xor(s1, 16); s1 += __shfl_xor(s1, 32);
        if (lane < 16) { S[0][col] = s0; S[1][col] = s1; }
    }
    __syncthreads();

    // ---- comm: c = (colsum - h1)/32 : T1 -> T0 (per-batch colsum), vectorized half8
    {
        #pragma unroll
        for (int it = 0; it < 2; it++) {
            int i  = tid + it * 1024;       // 2048 chunks total
            int r  = i >> 5;                // row 0..63
            int c8 = (i & 31) << 3;
            const float* Sp = &S[r >> 5][0];
            half8 hv = *(const half8*)(&sA[1][r * SA + c8]);
            float4v t0 = *(const float4v*)(Sp + c8);
            float4v t1 = *(const float4v*)(Sp + c8 + 4);
            half8 cv;
            cv[0] = (_Float16)((t0[0] - (float)hv[0]) * (1.f / 32.f));
            cv[1] = (_Float16)((t0[1] - (float)hv[1]) * (1.f / 32.f));
            cv[2] = (_Float16)((t0[2] - (float)hv[2]) * (1.f / 32.f));
            cv[3] = (_Float16)((t0[3] - (float)hv[3]) * (1.f / 32.f));
            cv[4] = (_Float16)((t1[0] - (float)hv[4]) * (1.f / 32.f));
            cv[5] = (_Float16)((t1[1] - (float)hv[5]) * (1.f / 32.f));
            cv[6] = (_Float16)((t1[2] - (float)hv[6]) * (1.f / 32.f));
            cv[7] = (_Float16)((t1[3] - (float)hv[7]) * (1.f / 32.f));
            *(half8*)(&sA[0][r * SA + c8]) = cv;
        }
        if (tid < MROWS) Srow[tid] = 0.f;   // decoder row accumulators
    }
    __syncthreads();

    // ---- GRU2 fused: gi from c (T0) @ W_ih, gh from h1 (T1) @ W_hh.
    // r,z gates share accumulators (sigmoid of gi+gh); n needs both halves.
    {
        float4v aR[4], aZ[4], aNi[4], aNh[4];
        float4v z = {0.f, 0.f, 0.f, 0.f};
        #pragma unroll
        for (int mt = 0; mt < 4; mt++) { aR[mt] = z; aZ[mt] = z; aNi[mt] = z; aNh[mt] = z; }
        #pragma unroll 2
        for (int ks = 0; ks < 8; ks++) {
            const int kbase = ks * 32 + kq;
            // gi side: A = c
            {
                half8 Cf[4];
                #pragma unroll
                for (int mt = 0; mt < 4; mt++)
                    Cf[mt] = *(const half8*)(&sA[0][(mt * 16 + l16) * SA + kbase]);
                half8 bR = ldB(prep + WIH_OFF, 48,  0 + w, ks, wih, HID, use_prep, lane);
                half8 bZ = ldB(prep + WIH_OFF, 48, 16 + w, ks, wih, HID, use_prep, lane);
                half8 bN = ldB(prep + WIH_OFF, 48, 32 + w, ks, wih, HID, use_prep, lane);
                #pragma unroll
                for (int mt = 0; mt < 4; mt++)
                    aR[mt]  = __builtin_amdgcn_mfma_f32_16x16x32_f16(Cf[mt], bR, aR[mt], 0, 0, 0);
                #pragma unroll
                for (int mt = 0; mt < 4; mt++)
                    aZ[mt]  = __builtin_amdgcn_mfma_f32_16x16x32_f16(Cf[mt], bZ, aZ[mt], 0, 0, 0);
                #pragma unroll
                for (int mt = 0; mt < 4; mt++)
                    aNi[mt] = __builtin_amdgcn_mfma_f32_16x16x32_f16(Cf[mt], bN, aNi[mt], 0, 0, 0);
            }
            // gh side: A = h1
            {
                half8 Hf[4];
                #pragma unroll
                for (int mt = 0; mt < 4; mt++)
                    Hf[mt] = *(const half8*)(&sA[1][(mt * 16 + l16) * SA + kbase]);
                half8 bR = ldB(prep + WHH_OFF, 48,  0 + w, ks, whh, HID, use_prep, lane);
                half8 bZ = ldB(prep + WHH_OFF, 48, 16 + w, ks, whh, HID, use_prep, lane);
                half8 bN = ldB(prep + WHH_OFF, 48, 32 + w, ks, whh, HID, use_prep, lane);
                #pragma unroll
                for (int mt = 0; mt < 4; mt++)
                    aR[mt]  = __builtin_amdgcn_mfma_f32_16x16x32_f16(Hf[mt], bR, aR[mt], 0, 0, 0);
                #pragma unroll
                for (int mt = 0; mt < 4; mt++)
                    aZ[mt]  = __builtin_amdgcn_mfma_f32_16x16x32_f16(Hf[mt], bZ, aZ[mt], 0, 0, 0);
                #pragma unroll
                for (int mt = 0; mt < 4; mt++)
                    aNh[mt] = __builtin_amdgcn_mfma_f32_16x16x32_f16(Hf[mt], bN, aNh[mt], 0, 0, 0);
            }
        }

        // ---- epilogue + decoder fold: out[row] = sum_col h2*dec_W[col] + dec_b
        float biR = b_ih[col],       bhR = b_hh[col];
        float biZ = b_ih[256 + col], bhZ = b_hh[256 + col];
        float biN = b_ih[512 + col], bhN = b_hh[512 + col];
        float dw  = dec_W[col];
        float p[4][4];
        #pragma unroll
        for (int mt = 0; mt < 4; mt++)
            #pragma unroll
            for (int r = 0; r < 4; r++) {
                int row = mt * 16 + quad * 4 + r;
                float rg = sigmoid_f(aR[mt][r] + biR + bhR);
                float zg = sigmoid_f(aZ[mt][r] + biZ + bhZ);
                float ng = tanh_f((aNi[mt][r] + biN) + rg * (aNh[mt][r] + bhN));
                float h1v = (float)sA[1][row * SA + col];
                float h2 = (1.f - zg) * ng + zg * h1v;
                p[mt][r] = h2 * dw;
            }
        #pragma unroll
        for (int m = 1; m <= 8; m <<= 1) {
            #pragma unroll
            for (int mt = 0; mt < 4; mt++)
                #pragma unroll
                for (int r = 0; r < 4; r++)
                    p[mt][r] += __shfl_xor(p[mt][r], m);
        }
        if (l16 == 0) {
            #pragma unroll
            for (int mt = 0; mt < 4; mt++)
                #pragma unroll
                for (int r = 0; r < 4; r++)
                    atomicAdd(&Srow[mt * 16 + quad * 4 + r], p[mt][r]);
        }
    }
    __syncthreads();
    if (tid < MROWS) out[(size_t)b * MROWS + tid] = Srow[tid] + dec_b[0];
}

extern "C" void kernel_launch(void* const* d_in, const int* in_sizes, int n_in,
                              void* d_out, int out_size, void* d_ws, size_t ws_size,
                              hipStream_t stream) {
    const float* obs   = (const float*)d_in[0];
    // d_in[1] (act) is unused by the reference
    const float* encW  = (const float*)d_in[2];
    const float* encb  = (const float*)d_in[3];
    const float* fobsW = (const float*)d_in[4];
    const float* fobsb = (const float*)d_in[5];
    const float* wih   = (const float*)d_in[6];
    const float* bih   = (const float*)d_in[7];
    const float* whh   = (const float*)d_in[8];
    const float* bhh   = (const float*)d_in[9];
    const float* decW  = (const float*)d_in[10];
    const float* decb  = (const float*)d_in[11];
    float* out = (float*)d_out;

    _Float16* prep = (_Float16*)d_ws;
    int use_prep = (ws_size >= (size_t)PREP_TOTAL * sizeof(_Float16)) ? 1 : 0;
    if (use_prep) {
        prep_weights<<<(PREP_TOTAL + 255) / 256, 256, 0, stream>>>(encW, fobsW, wih, whh, prep);
    }
    commnet_fused<<<NB / 2, 1024, 0, stream>>>(obs, prep, encb, fobsb, bih, bhh, decW, decb, out,
                                               encW, fobsW, wih, whh, use_prep);
}

// Round 4
// 242.560 us; speedup vs baseline: 1.1358x; 1.0129x over previous
//
#include <hip/hip_runtime.h>
#include <hip/hip_fp16.h>

// CommNet critic forward, fully fused: 1 workgroup = 2 batches (64 agent-rows).
// All GEMMs via v_mfma_f32_16x16x32_f16 (fp32 accumulate). B=2048,A=32,D=128,H=256.
// V5: amdgpu_waves_per_eu(4,4). V4's __launch_bounds__(1024,4) only sets MIN waves/EU
//     (an upper cap on VGPRs) -- the allocator still targeted 8 waves/SIMD (2 blocks/CU
//     by LDS) and chose 64 VGPR + ~120 B/thread scratch spill (WRITE_SIZE=123MB).
//     Pinning max waves/EU to 4 lets it allocate up to 128 VGPRs spill-free;
//     runtime occupancy is unchanged (16 waves/CU either way).

#define NB   2048
#define NA   32
#define DIN  128
#define HID  256
#define SA   264   // f16 row stride for activation LDS tiles (stride 528B -> even bank spread)
#define MROWS 64   // 2 batches x 32 agents

typedef _Float16 half8  __attribute__((ext_vector_type(8)));
typedef float    float4v __attribute__((ext_vector_type(4)));

// f16 weight-fragment arena layout in d_ws (element offsets)
#define ENC_OFF    0
#define FOBS_OFF   32768
#define WIH_OFF    98304
#define WHH_OFF    294912
#define PREP_TOTAL 491520   // f16 elements -> 983040 bytes needed in ws

// Pre-arrange weights into exact MFMA B-fragment order, f16:
// frag[((ks*NT + nt)*64 + lane)*8 + j] = W[nt*16 + lane%16][ks*32 + (lane/16)*8 + j]
__global__ void prep_weights(const float* __restrict__ encW, const float* __restrict__ fobsW,
                             const float* __restrict__ wih,  const float* __restrict__ whh,
                             _Float16* __restrict__ prep) {
    int F = blockIdx.x * 256 + threadIdx.x;
    if (F >= PREP_TOTAL) return;
    const float* src; int K, NT, local = F;
    if (F < FOBS_OFF)     { src = encW;  K = 128; NT = 16; }
    else if (F < WIH_OFF) { src = fobsW; K = 256; NT = 16; local = F - FOBS_OFF; }
    else if (F < WHH_OFF) { src = wih;   K = 256; NT = 48; local = F - WIH_OFF; }
    else                  { src = whh;   K = 256; NT = 48; local = F - WHH_OFF; }
    int j    = local & 7;
    int lane = (local >> 3) & 63;
    int t    = local >> 9;
    int nt   = t % NT;
    int ks   = t / NT;
    int col  = nt * 16 + (lane & 15);
    int k    = ks * 32 + ((lane >> 4) << 3) + j;
    prep[F] = (_Float16)src[col * K + k];
}

__device__ __forceinline__ float sigmoid_f(float x) {
    x = fminf(fmaxf(x, -30.f), 30.f);
    return 1.f / (1.f + __expf(-x));
}
__device__ __forceinline__ float tanh_f(float x) {
    x = fminf(fmaxf(x, -15.f), 15.f);
    float e = __expf(-2.f * x);
    return (1.f - e) / (1.f + e);
}

// Load one MFMA B-fragment (16 cols x 32 k) either from prepped arena or raw fp32.
__device__ __forceinline__ half8 ldB(const _Float16* __restrict__ prepm, int NT, int nt, int ks,
                                     const float* __restrict__ raw, int K, int use_prep, int lane) {
    if (use_prep)
        return *(const half8*)(prepm + (((ks * NT + nt) * 64 + lane) << 3));
    half8 b;
    int l16 = lane & 15, kq = (lane >> 4) << 3;
    #pragma unroll
    for (int j = 0; j < 8; j++)
        b[j] = (_Float16)raw[(nt * 16 + l16) * K + ks * 32 + kq + j];
    return b;
}

// One wave computes 64 rows x 16 cols (mt=0..3, single ntile) of a GEMM.
template<int KSTEPS>
__device__ __forceinline__ void gemm_col16(const _Float16* __restrict__ Abuf,
        const _Float16* __restrict__ prepm, int NT, int nt,
        const float* __restrict__ raw, int K, int use_prep,
        int lane, float4v acc[4])
{
    const int l16 = lane & 15;
    const int kq  = (lane >> 4) << 3;
    #pragma unroll 2
    for (int ks = 0; ks < KSTEPS; ks++) {
        int kbase = ks * 32 + kq;
        half8 Af[4];
        #pragma unroll
        for (int mt = 0; mt < 4; mt++)
            Af[mt] = *(const half8*)(Abuf + (mt * 16 + l16) * SA + kbase);
        half8 b0 = ldB(prepm, NT, nt, ks, raw, K, use_prep, lane);
        #pragma unroll
        for (int mt = 0; mt < 4; mt++)
            acc[mt] = __builtin_amdgcn_mfma_f32_16x16x32_f16(Af[mt], b0, acc[mt], 0, 0, 0);
    }
}

__global__ __launch_bounds__(1024)
__attribute__((amdgpu_waves_per_eu(4, 4)))
void commnet_fused(
    const float* __restrict__ obs, const _Float16* __restrict__ prep,
    const float* __restrict__ enc_b, const float* __restrict__ fobs_b,
    const float* __restrict__ b_ih, const float* __restrict__ b_hh,
    const float* __restrict__ dec_W, const float* __restrict__ dec_b,
    float* __restrict__ out,
    const float* __restrict__ encW, const float* __restrict__ fobsW,
    const float* __restrict__ wih, const float* __restrict__ whh,
    int use_prep)
{
    const int b    = blockIdx.x;       // block handles batches 2b, 2b+1 (rows 0..63)
    const int tid  = threadIdx.x;
    const int lane = tid & 63;
    const int w    = tid >> 6;         // wave 0..15 -> col tile w (cols 16w..16w+15)
    const int l16  = lane & 15;
    const int quad = lane >> 4;
    const int kq   = quad << 3;
    const int col  = w * 16 + l16;     // this lane's output column (fixed all phases)

    __shared__ __align__(16) _Float16 sA[2][MROWS * SA];
    __shared__ __align__(16) float S[2][HID];   // per-batch column sums of h1
    __shared__ float Srow[MROWS];               // decoder row accumulators

    // ---- stage obs (fp32 global -> f16 LDS): 64 rows x 128, one half8 per thread
    {
        const float* obsb = obs + (size_t)b * MROWS * DIN;
        int r   = tid >> 4;            // 16 chunks per 128-wide row, 64 rows
        int off = (tid & 15) << 3;
        const float* src = obsb + r * DIN + off;
        float4v v0 = *(const float4v*)(src);
        float4v v1 = *(const float4v*)(src + 4);
        half8 hv;
        hv[0] = (_Float16)v0[0]; hv[1] = (_Float16)v0[1];
        hv[2] = (_Float16)v0[2]; hv[3] = (_Float16)v0[3];
        hv[4] = (_Float16)v1[0]; hv[5] = (_Float16)v1[1];
        hv[6] = (_Float16)v1[2]; hv[7] = (_Float16)v1[3];
        *(half8*)(&sA[0][r * SA + off]) = hv;
    }
    __syncthreads();

    float4v acc[4];

    // ---- encoder: e = relu(obs @ encW^T + enc_b) : T0 -> T1
    {
        float4v z = {0.f, 0.f, 0.f, 0.f};
        acc[0] = z; acc[1] = z; acc[2] = z; acc[3] = z;
        gemm_col16<4>(&sA[0][0], prep + ENC_OFF, 16, w, encW, DIN, use_prep, lane, acc);
        float bb = enc_b[col];
        #pragma unroll
        for (int mt = 0; mt < 4; mt++)
            #pragma unroll
            for (int r = 0; r < 4; r++) {
                int row = mt * 16 + quad * 4 + r;
                sA[1][row * SA + col] = (_Float16)fmaxf(acc[mt][r] + bb, 0.f);
            }
    }
    __syncthreads();

    // ---- fobs: h = e @ fobsW^T + fobs_b : T1 -> T0
    {
        float4v z = {0.f, 0.f, 0.f, 0.f};
        acc[0] = z; acc[1] = z; acc[2] = z; acc[3] = z;
        gemm_col16<8>(&sA[1][0], prep + FOBS_OFF, 16, w, fobsW, HID, use_prep, lane, acc);
        float bb = fobs_b[col];
        #pragma unroll
        for (int mt = 0; mt < 4; mt++)
            #pragma unroll
            for (int r = 0; r < 4; r++) {
                int row = mt * 16 + quad * 4 + r;
                sA[0][row * SA + col] = (_Float16)(acc[mt][r] + bb);
            }
    }
    __syncthreads();

    // ---- GRU1 fused (x=0 so gi = b_ih). A = T0 (h). One K-pass, 3 gate acc sets.
    {
        float4v aR[4], aZ[4], aN[4];
        float4v z = {0.f, 0.f, 0.f, 0.f};
        #pragma unroll
        for (int mt = 0; mt < 4; mt++) { aR[mt] = z; aZ[mt] = z; aN[mt] = z; }
        #pragma unroll 2
        for (int ks = 0; ks < 8; ks++) {
            const int kbase = ks * 32 + kq;
            half8 Af[4];
            #pragma unroll
            for (int mt = 0; mt < 4; mt++)
                Af[mt] = *(const half8*)(&sA[0][(mt * 16 + l16) * SA + kbase]);
            half8 bR = ldB(prep + WHH_OFF, 48,  0 + w, ks, whh, HID, use_prep, lane);
            half8 bZ = ldB(prep + WHH_OFF, 48, 16 + w, ks, whh, HID, use_prep, lane);
            half8 bN = ldB(prep + WHH_OFF, 48, 32 + w, ks, whh, HID, use_prep, lane);
            #pragma unroll
            for (int mt = 0; mt < 4; mt++)
                aR[mt] = __builtin_amdgcn_mfma_f32_16x16x32_f16(Af[mt], bR, aR[mt], 0, 0, 0);
            #pragma unroll
            for (int mt = 0; mt < 4; mt++)
                aZ[mt] = __builtin_amdgcn_mfma_f32_16x16x32_f16(Af[mt], bZ, aZ[mt], 0, 0, 0);
            #pragma unroll
            for (int mt = 0; mt < 4; mt++)
                aN[mt] = __builtin_amdgcn_mfma_f32_16x16x32_f16(Af[mt], bN, aN[mt], 0, 0, 0);
        }
        float biR = b_ih[col],       bhR = b_hh[col];
        float biZ = b_ih[256 + col], bhZ = b_hh[256 + col];
        float biN = b_ih[512 + col], bhN = b_hh[512 + col];
        float s0 = 0.f, s1 = 0.f;
        #pragma unroll
        for (int mt = 0; mt < 4; mt++) {
            float psum = 0.f;
            #pragma unroll
            for (int r = 0; r < 4; r++) {
                int row = mt * 16 + quad * 4 + r;
                float rg = sigmoid_f(biR + aR[mt][r] + bhR);
                float zg = sigmoid_f(biZ + aZ[mt][r] + bhZ);
                float ng = tanh_f(biN + rg * (aN[mt][r] + bhN));
                float hold = (float)sA[0][row * SA + col];
                float h1 = (1.f - zg) * ng + zg * hold;
                sA[1][row * SA + col] = (_Float16)h1;   // h1 -> T1
                psum += h1;
            }
            if (mt < 2) s0 += psum; else s1 += psum;
        }
        // column sums across the 4 quads (rows within each batch) -> S, no atomics
        s0 += __shfl_xor(s0, 16); s0 += __shfl_xor(s0, 32);
        s1 += __shfl_xor(s1, 16); s1 += __shfl_xor(s1, 32);
        if (lane < 16) { S[0][col] = s0; S[1][col] = s1; }
    }
    __syncthreads();

    // ---- comm: c = (colsum - h1)/32 : T1 -> T0 (per-batch colsum), vectorized half8
    {
        #pragma unroll
        for (int it = 0; it < 2; it++) {
            int i  = tid + it * 1024;       // 2048 chunks total
            int r  = i >> 5;                // row 0..63
            int c8 = (i & 31) << 3;
            const float* Sp = &S[r >> 5][0];
            half8 hv = *(const half8*)(&sA[1][r * SA + c8]);
            float4v t0 = *(const float4v*)(Sp + c8);
            float4v t1 = *(const float4v*)(Sp + c8 + 4);
            half8 cv;
            cv[0] = (_Float16)((t0[0] - (float)hv[0]) * (1.f / 32.f));
            cv[1] = (_Float16)((t0[1] - (float)hv[1]) * (1.f / 32.f));
            cv[2] = (_Float16)((t0[2] - (float)hv[2]) * (1.f / 32.f));
            cv[3] = (_Float16)((t0[3] - (float)hv[3]) * (1.f / 32.f));
            cv[4] = (_Float16)((t1[0] - (float)hv[4]) * (1.f / 32.f));
            cv[5] = (_Float16)((t1[1] - (float)hv[5]) * (1.f / 32.f));
            cv[6] = (_Float16)((t1[2] - (float)hv[6]) * (1.f / 32.f));
            cv[7] = (_Float16)((t1[3] - (float)hv[7]) * (1.f / 32.f));
            *(half8*)(&sA[0][r * SA + c8]) = cv;
        }
        if (tid < MROWS) Srow[tid] = 0.f;   // decoder row accumulators
    }
    __syncthreads();

    // ---- GRU2 fused: gi from c (T0) @ W_ih, gh from h1 (T1) @ W_hh.
    // r,z gates share accumulators (sigmoid of gi+gh); n needs both halves.
    {
        float4v aR[4], aZ[4], aNi[4], aNh[4];
        float4v z = {0.f, 0.f, 0.f, 0.f};
        #pragma unroll
        for (int mt = 0; mt < 4; mt++) { aR[mt] = z; aZ[mt] = z; aNi[mt] = z; aNh[mt] = z; }
        #pragma unroll 2
        for (int ks = 0; ks < 8; ks++) {
            const int kbase = ks * 32 + kq;
            // gi side: A = c
            {
                half8 Cf[4];
                #pragma unroll
                for (int mt = 0; mt < 4; mt++)
                    Cf[mt] = *(const half8*)(&sA[0][(mt * 16 + l16) * SA + kbase]);
                half8 bR = ldB(prep + WIH_OFF, 48,  0 + w, ks, wih, HID, use_prep, lane);
                half8 bZ = ldB(prep + WIH_OFF, 48, 16 + w, ks, wih, HID, use_prep, lane);
                half8 bN = ldB(prep + WIH_OFF, 48, 32 + w, ks, wih, HID, use_prep, lane);
                #pragma unroll
                for (int mt = 0; mt < 4; mt++)
                    aR[mt]  = __builtin_amdgcn_mfma_f32_16x16x32_f16(Cf[mt], bR, aR[mt], 0, 0, 0);
                #pragma unroll
                for (int mt = 0; mt < 4; mt++)
                    aZ[mt]  = __builtin_amdgcn_mfma_f32_16x16x32_f16(Cf[mt], bZ, aZ[mt], 0, 0, 0);
                #pragma unroll
                for (int mt = 0; mt < 4; mt++)
                    aNi[mt] = __builtin_amdgcn_mfma_f32_16x16x32_f16(Cf[mt], bN, aNi[mt], 0, 0, 0);
            }
            // gh side: A = h1
            {
                half8 Hf[4];
                #pragma unroll
                for (int mt = 0; mt < 4; mt++)
                    Hf[mt] = *(const half8*)(&sA[1][(mt * 16 + l16) * SA + kbase]);
                half8 bR = ldB(prep + WHH_OFF, 48,  0 + w, ks, whh, HID, use_prep, lane);
                half8 bZ = ldB(prep + WHH_OFF, 48, 16 + w, ks, whh, HID, use_prep, lane);
                half8 bN = ldB(prep + WHH_OFF, 48, 32 + w, ks, whh, HID, use_prep, lane);
                #pragma unroll
                for (int mt = 0; mt < 4; mt++)
                    aR[mt]  = __builtin_amdgcn_mfma_f32_16x16x32_f16(Hf[mt], bR, aR[mt], 0, 0, 0);
                #pragma unroll
                for (int mt = 0; mt < 4; mt++)
                    aZ[mt]  = __builtin_amdgcn_mfma_f32_16x16x32_f16(Hf[mt], bZ, aZ[mt], 0, 0, 0);
                #pragma unroll
                for (int mt = 0; mt < 4; mt++)
                    aNh[mt] = __builtin_amdgcn_mfma_f32_16x16x32_f16(Hf[mt], bN, aNh[mt], 0, 0, 0);
            }
        }

        // ---- epilogue + decoder fold: out[row] = sum_col h2*dec_W[col] + dec_b
        float biR = b_ih[col],       bhR = b_hh[col];
        float biZ = b_ih[256 + col], bhZ = b_hh[256 + col];
        float biN = b_ih[512 + col], bhN = b_hh[512 + col];
        float dw  = dec_W[col];
        float p[4][4];
        #pragma unroll
        for (int mt = 0; mt < 4; mt++)
            #pragma unroll
            for (int r = 0; r < 4; r++) {
                int row = mt * 16 + quad * 4 + r;
                float rg = sigmoid_f(aR[mt][r] + biR + bhR);
                float zg = sigmoid_f(aZ[mt][r] + biZ + bhZ);
                float ng = tanh_f((aNi[mt][r] + biN) + rg * (aNh[mt][r] + bhN));
                float h1v = (float)sA[1][row * SA + col];
                float h2 = (1.f - zg) * ng + zg * h1v;
                p[mt][r] = h2 * dw;
            }
        #pragma unroll
        for (int m = 1; m <= 8; m <<= 1) {
            #pragma unroll
            for (int mt = 0; mt < 4; mt++)
                #pragma unroll
                for (int r = 0; r < 4; r++)
                    p[mt][r] += __shfl_xor(p[mt][r], m);
        }
        if (l16 == 0) {
            #pragma unroll
            for (int mt = 0; mt < 4; mt++)
                #pragma unroll
                for (int r = 0; r < 4; r++)
                    atomicAdd(&Srow[mt * 16 + quad * 4 + r], p[mt][r]);
        }
    }
    __syncthreads();
    if (tid < MROWS) out[(size_t)b * MROWS + tid] = Srow[tid] + dec_b[0];
}

extern "C" void kernel_launch(void* const* d_in, const int* in_sizes, int n_in,
                              void* d_out, int out_size, void* d_ws, size_t ws_size,
                              hipStream_t stream) {
    const float* obs   = (const float*)d_in[0];
    // d_in[1] (act) is unused by the reference
    const float* encW  = (const float*)d_in[2];
    const float* encb  = (const float*)d_in[3];
    const float* fobsW = (const float*)d_in[4];
    const float* fobsb = (const float*)d_in[5];
    const float* wih   = (const float*)d_in[6];
    const float* bih   = (const float*)d_in[7];
    const float* whh   = (const float*)d_in[8];
    const float* bhh   = (const float*)d_in[9];
    const float* decW  = (const float*)d_in[10];
    const float* decb  = (const float*)d_in[11];
    float* out = (float*)d_out;

    _Float16* prep = (_Float16*)d_ws;
    int use_prep = (ws_size >= (size_t)PREP_TOTAL * sizeof(_Float16)) ? 1 : 0;
    if (use_prep) {
        prep_weights<<<(PREP_TOTAL + 255) / 256, 256, 0, stream>>>(encW, fobsW, wih, whh, prep);
    }
    commnet_fused<<<NB / 2, 1024, 0, stream>>>(obs, prep, encb, fobsb, bih, bhh, decW, decb, out,
                                               encW, fobsW, wih, whh, use_prep);
}

// Round 5
// 242.212 us; speedup vs baseline: 1.1374x; 1.0014x over previous
//
#include <hip/hip_runtime.h>
#include <hip/hip_fp16.h>

// CommNet critic forward, fully fused: 1 workgroup = 2 batches (64 agent-rows).
// All GEMMs via v_mfma_f32_16x16x32_f16 (fp32 accumulate). B=2048,A=32,D=128,H=256.
// V6: SA 264 -> 328 pushes LDS to 86.3KB (> 80KB) so only 1 block/CU fits.
//     The register allocator budgets VGPRs for the LDS-derived max occupancy
//     (2 blocks/CU = 8 waves/EU -> 64 VGPR + ~27 reg/thread scratch spill,
//     WRITE_SIZE=115MB; attributes alone didn't move it in V4/V5). With
//     1 block/CU the target is 4 waves/EU -> 128-VGPR budget, spill-free.
//     Bank stagger preserved: 328 f16 = 656B = 164 dwords, 164 mod 32 = 4.

#define NB   2048
#define NA   32
#define DIN  128
#define HID  256
#define SA   328   // f16 row stride for activation LDS tiles (656B stride -> 4-bank stagger)
#define MROWS 64   // 2 batches x 32 agents

typedef _Float16 half8  __attribute__((ext_vector_type(8)));
typedef float    float4v __attribute__((ext_vector_type(4)));

// f16 weight-fragment arena layout in d_ws (element offsets)
#define ENC_OFF    0
#define FOBS_OFF   32768
#define WIH_OFF    98304
#define WHH_OFF    294912
#define PREP_TOTAL 491520   // f16 elements -> 983040 bytes needed in ws

// Pre-arrange weights into exact MFMA B-fragment order, f16:
// frag[((ks*NT + nt)*64 + lane)*8 + j] = W[nt*16 + lane%16][ks*32 + (lane/16)*8 + j]
__global__ void prep_weights(const float* __restrict__ encW, const float* __restrict__ fobsW,
                             const float* __restrict__ wih,  const float* __restrict__ whh,
                             _Float16* __restrict__ prep) {
    int F = blockIdx.x * 256 + threadIdx.x;
    if (F >= PREP_TOTAL) return;
    const float* src; int K, NT, local = F;
    if (F < FOBS_OFF)     { src = encW;  K = 128; NT = 16; }
    else if (F < WIH_OFF) { src = fobsW; K = 256; NT = 16; local = F - FOBS_OFF; }
    else if (F < WHH_OFF) { src = wih;   K = 256; NT = 48; local = F - WIH_OFF; }
    else                  { src = whh;   K = 256; NT = 48; local = F - WHH_OFF; }
    int j    = local & 7;
    int lane = (local >> 3) & 63;
    int t    = local >> 9;
    int nt   = t % NT;
    int ks   = t / NT;
    int col  = nt * 16 + (lane & 15);
    int k    = ks * 32 + ((lane >> 4) << 3) + j;
    prep[F] = (_Float16)src[col * K + k];
}

__device__ __forceinline__ float sigmoid_f(float x) {
    x = fminf(fmaxf(x, -30.f), 30.f);
    return 1.f / (1.f + __expf(-x));
}
__device__ __forceinline__ float tanh_f(float x) {
    x = fminf(fmaxf(x, -15.f), 15.f);
    float e = __expf(-2.f * x);
    return (1.f - e) / (1.f + e);
}

// Load one MFMA B-fragment (16 cols x 32 k) either from prepped arena or raw fp32.
__device__ __forceinline__ half8 ldB(const _Float16* __restrict__ prepm, int NT, int nt, int ks,
                                     const float* __restrict__ raw, int K, int use_prep, int lane) {
    if (use_prep)
        return *(const half8*)(prepm + (((ks * NT + nt) * 64 + lane) << 3));
    half8 b;
    int l16 = lane & 15, kq = (lane >> 4) << 3;
    #pragma unroll
    for (int j = 0; j < 8; j++)
        b[j] = (_Float16)raw[(nt * 16 + l16) * K + ks * 32 + kq + j];
    return b;
}

// One wave computes 64 rows x 16 cols (mt=0..3, single ntile) of a GEMM.
template<int KSTEPS>
__device__ __forceinline__ void gemm_col16(const _Float16* __restrict__ Abuf,
        const _Float16* __restrict__ prepm, int NT, int nt,
        const float* __restrict__ raw, int K, int use_prep,
        int lane, float4v acc[4])
{
    const int l16 = lane & 15;
    const int kq  = (lane >> 4) << 3;
    #pragma unroll 2
    for (int ks = 0; ks < KSTEPS; ks++) {
        int kbase = ks * 32 + kq;
        half8 Af[4];
        #pragma unroll
        for (int mt = 0; mt < 4; mt++)
            Af[mt] = *(const half8*)(Abuf + (mt * 16 + l16) * SA + kbase);
        half8 b0 = ldB(prepm, NT, nt, ks, raw, K, use_prep, lane);
        #pragma unroll
        for (int mt = 0; mt < 4; mt++)
            acc[mt] = __builtin_amdgcn_mfma_f32_16x16x32_f16(Af[mt], b0, acc[mt], 0, 0, 0);
    }
}

__global__ __launch_bounds__(1024)
__attribute__((amdgpu_waves_per_eu(4, 4)))
void commnet_fused(
    const float* __restrict__ obs, const _Float16* __restrict__ prep,
    const float* __restrict__ enc_b, const float* __restrict__ fobs_b,
    const float* __restrict__ b_ih, const float* __restrict__ b_hh,
    const float* __restrict__ dec_W, const float* __restrict__ dec_b,
    float* __restrict__ out,
    const float* __restrict__ encW, const float* __restrict__ fobsW,
    const float* __restrict__ wih, const float* __restrict__ whh,
    int use_prep)
{
    const int b    = blockIdx.x;       // block handles batches 2b, 2b+1 (rows 0..63)
    const int tid  = threadIdx.x;
    const int lane = tid & 63;
    const int w    = tid >> 6;         // wave 0..15 -> col tile w (cols 16w..16w+15)
    const int l16  = lane & 15;
    const int quad = lane >> 4;
    const int kq   = quad << 3;
    const int col  = w * 16 + l16;     // this lane's output column (fixed all phases)

    __shared__ __align__(16) _Float16 sA[2][MROWS * SA];
    __shared__ __align__(16) float S[2][HID];   // per-batch column sums of h1
    __shared__ float Srow[MROWS];               // decoder row accumulators

    // ---- stage obs (fp32 global -> f16 LDS): 64 rows x 128, one half8 per thread
    {
        const float* obsb = obs + (size_t)b * MROWS * DIN;
        int r   = tid >> 4;            // 16 chunks per 128-wide row, 64 rows
        int off = (tid & 15) << 3;
        const float* src = obsb + r * DIN + off;
        float4v v0 = *(const float4v*)(src);
        float4v v1 = *(const float4v*)(src + 4);
        half8 hv;
        hv[0] = (_Float16)v0[0]; hv[1] = (_Float16)v0[1];
        hv[2] = (_Float16)v0[2]; hv[3] = (_Float16)v0[3];
        hv[4] = (_Float16)v1[0]; hv[5] = (_Float16)v1[1];
        hv[6] = (_Float16)v1[2]; hv[7] = (_Float16)v1[3];
        *(half8*)(&sA[0][r * SA + off]) = hv;
    }
    __syncthreads();

    float4v acc[4];

    // ---- encoder: e = relu(obs @ encW^T + enc_b) : T0 -> T1
    {
        float4v z = {0.f, 0.f, 0.f, 0.f};
        acc[0] = z; acc[1] = z; acc[2] = z; acc[3] = z;
        gemm_col16<4>(&sA[0][0], prep + ENC_OFF, 16, w, encW, DIN, use_prep, lane, acc);
        float bb = enc_b[col];
        #pragma unroll
        for (int mt = 0; mt < 4; mt++)
            #pragma unroll
            for (int r = 0; r < 4; r++) {
                int row = mt * 16 + quad * 4 + r;
                sA[1][row * SA + col] = (_Float16)fmaxf(acc[mt][r] + bb, 0.f);
            }
    }
    __syncthreads();

    // ---- fobs: h = e @ fobsW^T + fobs_b : T1 -> T0
    {
        float4v z = {0.f, 0.f, 0.f, 0.f};
        acc[0] = z; acc[1] = z; acc[2] = z; acc[3] = z;
        gemm_col16<8>(&sA[1][0], prep + FOBS_OFF, 16, w, fobsW, HID, use_prep, lane, acc);
        float bb = fobs_b[col];
        #pragma unroll
        for (int mt = 0; mt < 4; mt++)
            #pragma unroll
            for (int r = 0; r < 4; r++) {
                int row = mt * 16 + quad * 4 + r;
                sA[0][row * SA + col] = (_Float16)(acc[mt][r] + bb);
            }
    }
    __syncthreads();

    // ---- GRU1 fused (x=0 so gi = b_ih). A = T0 (h). One K-pass, 3 gate acc sets.
    {
        float4v aR[4], aZ[4], aN[4];
        float4v z = {0.f, 0.f, 0.f, 0.f};
        #pragma unroll
        for (int mt = 0; mt < 4; mt++) { aR[mt] = z; aZ[mt] = z; aN[mt] = z; }
        #pragma unroll 2
        for (int ks = 0; ks < 8; ks++) {
            const int kbase = ks * 32 + kq;
            half8 Af[4];
            #pragma unroll
            for (int mt = 0; mt < 4; mt++)
                Af[mt] = *(const half8*)(&sA[0][(mt * 16 + l16) * SA + kbase]);
            half8 bR = ldB(prep + WHH_OFF, 48,  0 + w, ks, whh, HID, use_prep, lane);
            half8 bZ = ldB(prep + WHH_OFF, 48, 16 + w, ks, whh, HID, use_prep, lane);
            half8 bN = ldB(prep + WHH_OFF, 48, 32 + w, ks, whh, HID, use_prep, lane);
            #pragma unroll
            for (int mt = 0; mt < 4; mt++)
                aR[mt] = __builtin_amdgcn_mfma_f32_16x16x32_f16(Af[mt], bR, aR[mt], 0, 0, 0);
            #pragma unroll
            for (int mt = 0; mt < 4; mt++)
                aZ[mt] = __builtin_amdgcn_mfma_f32_16x16x32_f16(Af[mt], bZ, aZ[mt], 0, 0, 0);
            #pragma unroll
            for (int mt = 0; mt < 4; mt++)
                aN[mt] = __builtin_amdgcn_mfma_f32_16x16x32_f16(Af[mt], bN, aN[mt], 0, 0, 0);
        }
        float biR = b_ih[col],       bhR = b_hh[col];
        float biZ = b_ih[256 + col], bhZ = b_hh[256 + col];
        float biN = b_ih[512 + col], bhN = b_hh[512 + col];
        float s0 = 0.f, s1 = 0.f;
        #pragma unroll
        for (int mt = 0; mt < 4; mt++) {
            float psum = 0.f;
            #pragma unroll
            for (int r = 0; r < 4; r++) {
                int row = mt * 16 + quad * 4 + r;
                float rg = sigmoid_f(biR + aR[mt][r] + bhR);
                float zg = sigmoid_f(biZ + aZ[mt][r] + bhZ);
                float ng = tanh_f(biN + rg * (aN[mt][r] + bhN));
                float hold = (float)sA[0][row * SA + col];
                float h1 = (1.f - zg) * ng + zg * hold;
                sA[1][row * SA + col] = (_Float16)h1;   // h1 -> T1
                psum += h1;
            }
            if (mt < 2) s0 += psum; else s1 += psum;
        }
        // column sums across the 4 quads (rows within each batch) -> S, no atomics
        s0 += __shfl_xor(s0, 16); s0 += __shfl_xor(s0, 32);
        s1 += __shfl_xor(s1, 16); s1 += __shfl_xor(s1, 32);
        if (lane < 16) { S[0][col] = s0; S[1][col] = s1; }
    }
    __syncthreads();

    // ---- comm: c = (colsum - h1)/32 : T1 -> T0 (per-batch colsum), vectorized half8
    {
        #pragma unroll
        for (int it = 0; it < 2; it++) {
            int i  = tid + it * 1024;       // 2048 chunks total
            int r  = i >> 5;                // row 0..63
            int c8 = (i & 31) << 3;
            const float* Sp = &S[r >> 5][0];
            half8 hv = *(const half8*)(&sA[1][r * SA + c8]);
            float4v t0 = *(const float4v*)(Sp + c8);
            float4v t1 = *(const float4v*)(Sp + c8 + 4);
            half8 cv;
            cv[0] = (_Float16)((t0[0] - (float)hv[0]) * (1.f / 32.f));
            cv[1] = (_Float16)((t0[1] - (float)hv[1]) * (1.f / 32.f));
            cv[2] = (_Float16)((t0[2] - (float)hv[2]) * (1.f / 32.f));
            cv[3] = (_Float16)((t0[3] - (float)hv[3]) * (1.f / 32.f));
            cv[4] = (_Float16)((t1[0] - (float)hv[4]) * (1.f / 32.f));
            cv[5] = (_Float16)((t1[1] - (float)hv[5]) * (1.f / 32.f));
            cv[6] = (_Float16)((t1[2] - (float)hv[6]) * (1.f / 32.f));
            cv[7] = (_Float16)((t1[3] - (float)hv[7]) * (1.f / 32.f));
            *(half8*)(&sA[0][r * SA + c8]) = cv;
        }
        if (tid < MROWS) Srow[tid] = 0.f;   // decoder row accumulators
    }
    __syncthreads();

    // ---- GRU2 fused: gi from c (T0) @ W_ih, gh from h1 (T1) @ W_hh.
    // r,z gates share accumulators (sigmoid of gi+gh); n needs both halves.
    {
        float4v aR[4], aZ[4], aNi[4], aNh[4];
        float4v z = {0.f, 0.f, 0.f, 0.f};
        #pragma unroll
        for (int mt = 0; mt < 4; mt++) { aR[mt] = z; aZ[mt] = z; aNi[mt] = z; aNh[mt] = z; }
        #pragma unroll 2
        for (int ks = 0; ks < 8; ks++) {
            const int kbase = ks * 32 + kq;
            // gi side: A = c
            {
                half8 Cf[4];
                #pragma unroll
                for (int mt = 0; mt < 4; mt++)
                    Cf[mt] = *(const half8*)(&sA[0][(mt * 16 + l16) * SA + kbase]);
                half8 bR = ldB(prep + WIH_OFF, 48,  0 + w, ks, wih, HID, use_prep, lane);
                half8 bZ = ldB(prep + WIH_OFF, 48, 16 + w, ks, wih, HID, use_prep, lane);
                half8 bN = ldB(prep + WIH_OFF, 48, 32 + w, ks, wih, HID, use_prep, lane);
                #pragma unroll
                for (int mt = 0; mt < 4; mt++)
                    aR[mt]  = __builtin_amdgcn_mfma_f32_16x16x32_f16(Cf[mt], bR, aR[mt], 0, 0, 0);
                #pragma unroll
                for (int mt = 0; mt < 4; mt++)
                    aZ[mt]  = __builtin_amdgcn_mfma_f32_16x16x32_f16(Cf[mt], bZ, aZ[mt], 0, 0, 0);
                #pragma unroll
                for (int mt = 0; mt < 4; mt++)
                    aNi[mt] = __builtin_amdgcn_mfma_f32_16x16x32_f16(Cf[mt], bN, aNi[mt], 0, 0, 0);
            }
            // gh side: A = h1
            {
                half8 Hf[4];
                #pragma unroll
                for (int mt = 0; mt < 4; mt++)
                    Hf[mt] = *(const half8*)(&sA[1][(mt * 16 + l16) * SA + kbase]);
                half8 bR = ldB(prep + WHH_OFF, 48,  0 + w, ks, whh, HID, use_prep, lane);
                half8 bZ = ldB(prep + WHH_OFF, 48, 16 + w, ks, whh, HID, use_prep, lane);
                half8 bN = ldB(prep + WHH_OFF, 48, 32 + w, ks, whh, HID, use_prep, lane);
                #pragma unroll
                for (int mt = 0; mt < 4; mt++)
                    aR[mt]  = __builtin_amdgcn_mfma_f32_16x16x32_f16(Hf[mt], bR, aR[mt], 0, 0, 0);
                #pragma unroll
                for (int mt = 0; mt < 4; mt++)
                    aZ[mt]  = __builtin_amdgcn_mfma_f32_16x16x32_f16(Hf[mt], bZ, aZ[mt], 0, 0, 0);
                #pragma unroll
                for (int mt = 0; mt < 4; mt++)
                    aNh[mt] = __builtin_amdgcn_mfma_f32_16x16x32_f16(Hf[mt], bN, aNh[mt], 0, 0, 0);
            }
        }

        // ---- epilogue + decoder fold: out[row] = sum_col h2*dec_W[col] + dec_b
        float biR = b_ih[col],       bhR = b_hh[col];
        float biZ = b_ih[256 + col], bhZ = b_hh[256 + col];
        float biN = b_ih[512 + col], bhN = b_hh[512 + col];
        float dw  = dec_W[col];
        float p[4][4];
        #pragma unroll
        for (int mt = 0; mt < 4; mt++)
            #pragma unroll
            for (int r = 0; r < 4; r++) {
                int row = mt * 16 + quad * 4 + r;
                float rg = sigmoid_f(aR[mt][r] + biR + bhR);
                float zg = sigmoid_f(aZ[mt][r] + biZ + bhZ);
                float ng = tanh_f((aNi[mt][r] + biN) + rg * (aNh[mt][r] + bhN));
                float h1v = (float)sA[1][row * SA + col];
                float h2 = (1.f - zg) * ng + zg * h1v;
                p[mt][r] = h2 * dw;
            }
        #pragma unroll
        for (int m = 1; m <= 8; m <<= 1) {
            #pragma unroll
            for (int mt = 0; mt < 4; mt++)
                #pragma unroll
                for (int r = 0; r < 4; r++)
                    p[mt][r] += __shfl_xor(p[mt][r], m);
        }
        if (l16 == 0) {
            #pragma unroll
            for (int mt = 0; mt < 4; mt++)
                #pragma unroll
                for (int r = 0; r < 4; r++)
                    atomicAdd(&Srow[mt * 16 + quad * 4 + r], p[mt][r]);
        }
    }
    __syncthreads();
    if (tid < MROWS) out[(size_t)b * MROWS + tid] = Srow[tid] + dec_b[0];
}

extern "C" void kernel_launch(void* const* d_in, const int* in_sizes, int n_in,
                              void* d_out, int out_size, void* d_ws, size_t ws_size,
                              hipStream_t stream) {
    const float* obs   = (const float*)d_in[0];
    // d_in[1] (act) is unused by the reference
    const float* encW  = (const float*)d_in[2];
    const float* encb  = (const float*)d_in[3];
    const float* fobsW = (const float*)d_in[4];
    const float* fobsb = (const float*)d_in[5];
    const float* wih   = (const float*)d_in[6];
    const float* bih   = (const float*)d_in[7];
    const float* whh   = (const float*)d_in[8];
    const float* bhh   = (const float*)d_in[9];
    const float* decW  = (const float*)d_in[10];
    const float* decb  = (const float*)d_in[11];
    float* out = (float*)d_out;

    _Float16* prep = (_Float16*)d_ws;
    int use_prep = (ws_size >= (size_t)PREP_TOTAL * sizeof(_Float16)) ? 1 : 0;
    if (use_prep) {
        prep_weights<<<(PREP_TOTAL + 255) / 256, 256, 0, stream>>>(encW, fobsW, wih, whh, prep);
    }
    commnet_fused<<<NB / 2, 1024, 0, stream>>>(obs, prep, encb, fobsb, bih, bhh, decW, decb, out,
                                               encW, fobsW, wih, whh, use_prep);
}